// Round 6
// baseline (149.057 us; speedup 1.0000x reference)
//
#include <hip/hip_runtime.h>

// Problem constants (B,C,H,W)=(2,256,56,56), Cr=64, K=7, G=16, stride=1
#define HW     3136          // 56*56
#define C_IN   256
#define CR     64
#define KKG    784           // 49*16
#define NB     2             // batch
#define NPIX   6272          // NB*HW
#define NT25   25            // p-tiles of 256 over NPIX
#define BN_EPS 1e-5f

// Device-global scratch (fully rewritten every call; no cross-call state)
__device__ float g_P[4 * CR * NPIX];       // K-split conv1 partials [kc][o][p]
__device__ float g_T[CR * NPIX];           // conv1 output (pre-BN) [o][p]
__device__ float g_bs[2 * CR * NT25];      // per-block partial sum/sumsq [2][o][px]
__device__ float g_xg[16 * NPIX * 16];     // x transposed: [d][p][cg] = x[b][16cg+d][hw]
__device__ float g_w2t[CR * KKG];          // w2T[c][o] = w2[o][c]   (64 x 784)

// ---------------- K1a: conv1 partials (split-K by 4) | w2-transpose plane ----------------
// grid (25, 17, 4), block 256.
//   y < 16: conv1 partials, o0=y*4, kc=z. 1600 blocks.
//   y == 16: transpose w2 -> g_w2t (100 blocks, grid-stride).
__global__ __launch_bounds__(256) void k1a_conv1(const float* __restrict__ x,
                                                 const float* __restrict__ w1,
                                                 const float* __restrict__ w2) {
  if (blockIdx.y == 16) {
    int idx = (blockIdx.z * 25 + blockIdx.x) * 256 + threadIdx.x;
    for (int j = idx; j < CR * KKG; j += 100 * 256) {
      int c = j / KKG, o = j - c * KKG;      // w2T[c*784+o] = w2[o*64+c]
      g_w2t[j] = w2[o * CR + c];
    }
    return;
  }
  int p = blockIdx.x * 256 + threadIdx.x;   // [0, 6272)
  if (p >= NPIX) return;
  int o0 = blockIdx.y * 4;
  int kc = blockIdx.z;                      // input-channel chunk, 64 chans each
  int b  = p / HW;
  int u  = p - b * HW;

  const float* xb = x + ((size_t)(b * C_IN + kc * 64)) * HW + u;
  const float* w  = w1 + kc * 64;           // w1[o*256 + kc*64 + c]

  float a0 = 0.f, a1 = 0.f, a2 = 0.f, a3 = 0.f;
#pragma unroll 8
  for (int c = 0; c < 64; ++c) {
    float xv = xb[(size_t)c * HW];          // coalesced across lanes
    a0 += w[(o0 + 0) * C_IN + c] * xv;      // wave-uniform -> s_load
    a1 += w[(o0 + 1) * C_IN + c] * xv;
    a2 += w[(o0 + 2) * C_IN + c] * xv;
    a3 += w[(o0 + 3) * C_IN + c] * xv;
  }
  float* pp = g_P + ((size_t)kc * CR + o0) * NPIX + p;
  pp[0 * NPIX] = a0; pp[1 * NPIX] = a1; pp[2 * NPIX] = a2; pp[3 * NPIX] = a3;
}

// ---------------- kRT: fused (reduce partials -> T + partial stats) | (transpose x) ----
// grid (25, 80), block 256.
//   y in [0,64): reduce for o=y at p-tile x; write g_T and g_bs[o][px].
//   y in [64,80): transpose slice d=y-64 at p-tile x into g_xg.
__global__ __launch_bounds__(256) void kRT(const float* __restrict__ x,
                                           const float* __restrict__ b1) {
  int p = blockIdx.x * 256 + threadIdx.x;
  if (blockIdx.y < 64) {
    int o = blockIdx.y;
    bool valid = (p < NPIX);
    float v = 0.0f;
    if (valid) {
      v = b1[o]
        + g_P[((size_t)0 * CR + o) * NPIX + p]
        + g_P[((size_t)1 * CR + o) * NPIX + p]
        + g_P[((size_t)2 * CR + o) * NPIX + p]
        + g_P[((size_t)3 * CR + o) * NPIX + p];
      g_T[(size_t)o * NPIX + p] = v;
    }
    float s  = valid ? v : 0.0f;
    float s2 = valid ? v * v : 0.0f;
#pragma unroll
    for (int off = 32; off > 0; off >>= 1) {
      s  += __shfl_down(s, off);
      s2 += __shfl_down(s2, off);
    }
    __shared__ float sd[8];
    int lane = threadIdx.x & 63, wid = threadIdx.x >> 6;
    if (lane == 0) { sd[wid] = s; sd[4 + wid] = s2; }
    __syncthreads();
    if (threadIdx.x == 0) {
      g_bs[o * NT25 + blockIdx.x]             = sd[0] + sd[1] + sd[2] + sd[3];
      g_bs[CR * NT25 + o * NT25 + blockIdx.x] = sd[4] + sd[5] + sd[6] + sd[7];
    }
  } else {
    int d = blockIdx.y - 64;
    if (p >= NPIX) return;
    int b  = (p >= HW) ? 1 : 0;
    int hw = p - b * HW;
    const float* xp = x + ((size_t)(b * C_IN + d)) * HW + hw;
    float r[16];
#pragma unroll
    for (int cg = 0; cg < 16; ++cg)
      r[cg] = xp[(size_t)cg * (16 * HW)];
    float4* dst = (float4*)(g_xg + (((size_t)d * NPIX + p) << 4));
    dst[0] = make_float4(r[0], r[1], r[2], r[3]);
    dst[1] = make_float4(r[4], r[5], r[6], r[7]);
    dst[2] = make_float4(r[8], r[9], r[10], r[11]);
    dst[3] = make_float4(r[12], r[13], r[14], r[15]);
  }
}

// ---------------- kB: kout = w2 @ relu(BN(T)) + b2, BN finalized per-block ----------------
// grid (13, 49, 2), block 256. Each block: 16 output channels x 256 pixels.
// Weights via g_w2t: 64B contiguous per c-iter -> s_load_dwordx16.
__global__ __launch_bounds__(256) void kB_conv2(const float* __restrict__ gamma,
                                                const float* __restrict__ beta,
                                                const float* __restrict__ b2,
                                                float* __restrict__ kout) {
  __shared__ float ssc[CR], ssh[CR];
  if (threadIdx.x < CR) {
    int o = threadIdx.x;
    float S = 0.f, S2 = 0.f;
#pragma unroll
    for (int px = 0; px < NT25; ++px) {
      S  += g_bs[o * NT25 + px];
      S2 += g_bs[CR * NT25 + o * NT25 + px];
    }
    const float invN = 1.0f / (float)NPIX;
    float mean = S * invN;
    float var  = S2 * invN - mean * mean;   // population var matches jnp.var
    float inv  = rsqrtf(var + BN_EPS);
    float sc   = gamma[o] * inv;
    ssc[o] = sc;
    ssh[o] = beta[o] - mean * sc;
  }
  __syncthreads();

  int l  = blockIdx.x * 256 + threadIdx.x;
  if (l >= HW) return;
  int o0 = blockIdx.y * 16;
  int b  = blockIdx.z;

  float acc[16];
#pragma unroll
  for (int i = 0; i < 16; ++i) acc[i] = b2[o0 + i];

  const float* Tb = g_T + (size_t)b * HW + l;     // g_T[c*NPIX + b*HW + l]
  const float* wt = g_w2t + o0;                   // w2T[c*784 + o], 64B-aligned rows
#pragma unroll 4
  for (int c = 0; c < CR; ++c) {
    float tv = Tb[(size_t)c * NPIX];
    tv = fmaxf(tv * ssc[c] + ssh[c], 0.0f);       // fused BN + ReLU (LDS broadcast)
#pragma unroll
    for (int i = 0; i < 16; ++i)
      acc[i] += wt[c * KKG + i] * tv;             // contiguous uniform -> wide s_load
  }
  float* kb = kout + (size_t)(b * KKG + o0) * HW + l;
#pragma unroll
  for (int i = 0; i < 16; ++i) kb[(size_t)i * HW] = acc[i];
}

// ---------------- K4: involution, s-per-block, cg-split x4, float4 x-loads ----------
// out[b][16cg+s][u] = sum_kk kout[b][16kk+s][u] * x_g[d][b*HW+pix][cg]
//   d=(16kk+s)/49, kk'=(16kk+s)%49, ki=kk'/7, kj=kk'%7,
//   pix=(u/56+ki-3)*56 + (u%56+kj-3), term dropped if OOB.
// grid (13, 16, 8), block 256: x=u-tile, y=s (uniform), z=b*4+cg-quarter.
__global__ __launch_bounds__(256) void k4_invol(const float* __restrict__ kout,
                                                float* __restrict__ out) {
  int u = blockIdx.x * 256 + threadIdx.x;     // [0, 3136)
  if (u >= HW) return;
  int s   = blockIdx.y;                        // wave-uniform
  int bz  = blockIdx.z;
  int b   = bz >> 2;
  int cg0 = (bz & 3) * 4;

  int yrow = u / 56;
  int col  = u - yrow * 56;

  const float* kb = kout + (size_t)b * (KKG * HW) + (size_t)s * HW + u;
  const float* xg = g_xg + cg0;
  const size_t bHW16 = (size_t)(b * HW) << 4;

  float acc[4] = {0.f, 0.f, 0.f, 0.f};

#pragma unroll 7
  for (int kk = 0; kk < 49; ++kk) {
    int t16 = 16 * kk + s;          // scalar
    int d   = t16 / 49;             // scalar (SALU magic-mul)
    int kkp = t16 - d * 49;         // scalar
    int ki  = kkp / 7;              // scalar
    int kj  = kkp - ki * 7;         // scalar
    int yy = yrow + ki - 3, xx = col + kj - 3;
    float kv = kb[(size_t)kk * (16 * HW)];
    int off;
    if ((unsigned)yy < 56u && (unsigned)xx < 56u) {
      off = yy * 56 + xx;
    } else {
      off = 0;                      // safe address; kv=0 kills the term
      kv = 0.0f;
    }
    const float* xp = xg + (((size_t)d * NPIX + off) << 4) + bHW16;
    float4 xa = *(const float4*)xp;
    acc[0] += kv * xa.x;  acc[1] += kv * xa.y;
    acc[2] += kv * xa.z;  acc[3] += kv * xa.w;
  }

  // out channel c = 16*(cg0+cg) + s
  float* ob = out + (size_t)b * (C_IN * HW) + ((size_t)(16 * cg0 + s)) * HW + u;
#pragma unroll
  for (int cg = 0; cg < 4; ++cg) ob[(size_t)cg * (16 * HW)] = acc[cg];
}

extern "C" void kernel_launch(void* const* d_in, const int* in_sizes, int n_in,
                              void* d_out, int out_size, void* d_ws, size_t ws_size,
                              hipStream_t stream) {
  const float* x     = (const float*)d_in[0];
  const float* w1    = (const float*)d_in[1];
  const float* b1    = (const float*)d_in[2];
  const float* gamma = (const float*)d_in[3];
  const float* beta  = (const float*)d_in[4];
  const float* w2    = (const float*)d_in[5];
  const float* b2    = (const float*)d_in[6];

  float* out  = (float*)d_out;                       // (B,256,56,56)
  float* kout = out + (size_t)NB * C_IN * HW;        // (B,784,56,56) raw == (B,49,56,56,16)

  k1a_conv1<<<dim3(25, 17, 4), 256, 0, stream>>>(x, w1, w2);
  kRT<<<dim3(25, 80), 256, 0, stream>>>(x, b1);
  kB_conv2<<<dim3(13, 49, NB), 256, 0, stream>>>(gamma, beta, b2, kout);
  k4_invol<<<dim3(13, 16, 8), 256, 0, stream>>>(kout, out);
}

// Round 7
// 126.442 us; speedup vs baseline: 1.1789x; 1.1789x over previous
//
#include <hip/hip_runtime.h>

// Problem constants (B,C,H,W)=(2,256,56,56), Cr=64, K=7, G=16, stride=1
#define HW     3136          // 56*56
#define C_IN   256
#define CR     64
#define KKG    784           // 49*16
#define NB     2             // batch
#define NPIX   6272          // NB*HW
#define NT25   25            // p-tiles of 256 over NPIX
#define BN_EPS 1e-5f

// Device-global scratch (fully rewritten every call; no cross-call state)
__device__ float g_P[4 * CR * NPIX];       // K-split conv1 partials [kc][o][p]
__device__ float g_T[CR * NPIX];           // conv1 output (pre-BN) [o][p]
__device__ float g_bs[2 * CR * NT25];      // per-block partial sum/sumsq [2][o][px]
__device__ float g_xg[16 * NPIX * 16];     // x transposed: [d][p][cg] = x[b][16cg+d][hw]
__device__ float g_w2t[CR * KKG];          // w2T[c][o] = w2[o][c]   (64 x 784)

// ---------------- K1a: conv1 partials (split-K by 4) | w2-transpose plane ----------------
// grid (25, 17, 4), block 256.
//   y < 16: conv1 partials, o0=y*4, kc=z. 1600 blocks.
//   y == 16: transpose w2 -> g_w2t (100 blocks, grid-stride).
__global__ __launch_bounds__(256) void k1a_conv1(const float* __restrict__ x,
                                                 const float* __restrict__ w1,
                                                 const float* __restrict__ w2) {
  if (blockIdx.y == 16) {
    int idx = (blockIdx.z * 25 + blockIdx.x) * 256 + threadIdx.x;
    for (int j = idx; j < CR * KKG; j += 100 * 256) {
      int c = j / KKG, o = j - c * KKG;      // w2T[c*784+o] = w2[o*64+c]
      g_w2t[j] = w2[o * CR + c];
    }
    return;
  }
  int p = blockIdx.x * 256 + threadIdx.x;   // [0, 6272)
  if (p >= NPIX) return;
  int o0 = blockIdx.y * 4;
  int kc = blockIdx.z;                      // input-channel chunk, 64 chans each
  int b  = p / HW;
  int u  = p - b * HW;

  const float* xb = x + ((size_t)(b * C_IN + kc * 64)) * HW + u;
  const float* w  = w1 + kc * 64;           // w1[o*256 + kc*64 + c]

  float a0 = 0.f, a1 = 0.f, a2 = 0.f, a3 = 0.f;
#pragma unroll 8
  for (int c = 0; c < 64; ++c) {
    float xv = xb[(size_t)c * HW];          // coalesced across lanes
    a0 += w[(o0 + 0) * C_IN + c] * xv;      // wave-uniform -> s_load
    a1 += w[(o0 + 1) * C_IN + c] * xv;
    a2 += w[(o0 + 2) * C_IN + c] * xv;
    a3 += w[(o0 + 3) * C_IN + c] * xv;
  }
  float* pp = g_P + ((size_t)kc * CR + o0) * NPIX + p;
  pp[0 * NPIX] = a0; pp[1 * NPIX] = a1; pp[2 * NPIX] = a2; pp[3 * NPIX] = a3;
}

// ---------------- kRT: fused (reduce partials -> T + partial stats) | (transpose x) ----
// grid (25, 80), block 256.
//   y in [0,64): reduce for o=y at p-tile x; write g_T and g_bs[o][px].
//   y in [64,80): transpose slice d=y-64 at p-tile x into g_xg.
__global__ __launch_bounds__(256) void kRT(const float* __restrict__ x,
                                           const float* __restrict__ b1) {
  int p = blockIdx.x * 256 + threadIdx.x;
  if (blockIdx.y < 64) {
    int o = blockIdx.y;
    bool valid = (p < NPIX);
    float v = 0.0f;
    if (valid) {
      v = b1[o]
        + g_P[((size_t)0 * CR + o) * NPIX + p]
        + g_P[((size_t)1 * CR + o) * NPIX + p]
        + g_P[((size_t)2 * CR + o) * NPIX + p]
        + g_P[((size_t)3 * CR + o) * NPIX + p];
      g_T[(size_t)o * NPIX + p] = v;
    }
    float s  = valid ? v : 0.0f;
    float s2 = valid ? v * v : 0.0f;
#pragma unroll
    for (int off = 32; off > 0; off >>= 1) {
      s  += __shfl_down(s, off);
      s2 += __shfl_down(s2, off);
    }
    __shared__ float sd[8];
    int lane = threadIdx.x & 63, wid = threadIdx.x >> 6;
    if (lane == 0) { sd[wid] = s; sd[4 + wid] = s2; }
    __syncthreads();
    if (threadIdx.x == 0) {
      g_bs[o * NT25 + blockIdx.x]             = sd[0] + sd[1] + sd[2] + sd[3];
      g_bs[CR * NT25 + o * NT25 + blockIdx.x] = sd[4] + sd[5] + sd[6] + sd[7];
    }
  } else {
    int d = blockIdx.y - 64;
    if (p >= NPIX) return;
    int b  = (p >= HW) ? 1 : 0;
    int hw = p - b * HW;
    const float* xp = x + ((size_t)(b * C_IN + d)) * HW + hw;
    float r[16];
#pragma unroll
    for (int cg = 0; cg < 16; ++cg)
      r[cg] = xp[(size_t)cg * (16 * HW)];
    float4* dst = (float4*)(g_xg + (((size_t)d * NPIX + p) << 4));
    dst[0] = make_float4(r[0], r[1], r[2], r[3]);
    dst[1] = make_float4(r[4], r[5], r[6], r[7]);
    dst[2] = make_float4(r[8], r[9], r[10], r[11]);
    dst[3] = make_float4(r[12], r[13], r[14], r[15]);
  }
}

// ---------------- kB: kout = w2 @ relu(BN(T)) + b2, BN finalized per-block ----------------
// grid (13, 49, 2), block 256. Each block: 16 output channels x 256 pixels.
// Weights via g_w2t: 64B contiguous per c-iter -> wide s_load.
__global__ __launch_bounds__(256) void kB_conv2(const float* __restrict__ gamma,
                                                const float* __restrict__ beta,
                                                const float* __restrict__ b2,
                                                float* __restrict__ kout) {
  __shared__ float ssc[CR], ssh[CR];
  if (threadIdx.x < CR) {
    int o = threadIdx.x;
    float S = 0.f, S2 = 0.f;
#pragma unroll
    for (int px = 0; px < NT25; ++px) {
      S  += g_bs[o * NT25 + px];
      S2 += g_bs[CR * NT25 + o * NT25 + px];
    }
    const float invN = 1.0f / (float)NPIX;
    float mean = S * invN;
    float var  = S2 * invN - mean * mean;   // population var matches jnp.var
    float inv  = rsqrtf(var + BN_EPS);
    float sc   = gamma[o] * inv;
    ssc[o] = sc;
    ssh[o] = beta[o] - mean * sc;
  }
  __syncthreads();

  int l  = blockIdx.x * 256 + threadIdx.x;
  if (l >= HW) return;
  int o0 = blockIdx.y * 16;
  int b  = blockIdx.z;

  float acc[16];
#pragma unroll
  for (int i = 0; i < 16; ++i) acc[i] = b2[o0 + i];

  const float* Tb = g_T + (size_t)b * HW + l;     // g_T[c*NPIX + b*HW + l]
  const float* wt = g_w2t + o0;                   // w2T[c*784 + o], 64B-aligned rows
#pragma unroll 4
  for (int c = 0; c < CR; ++c) {
    float tv = Tb[(size_t)c * NPIX];
    tv = fmaxf(tv * ssc[c] + ssh[c], 0.0f);       // fused BN + ReLU (LDS broadcast)
#pragma unroll
    for (int i = 0; i < 16; ++i)
      acc[i] += wt[c * KKG + i] * tv;             // contiguous uniform -> wide s_load
  }
  float* kb = kout + (size_t)(b * KKG + o0) * HW + l;
#pragma unroll
  for (int i = 0; i < 16; ++i) kb[(size_t)i * HW] = acc[i];
}

// ---------------- K4: involution, s-per-block, FULL-LINE x_g loads (16 cg/thread) ----
// out[b][16cg+s][u] = sum_kk kout[b][16kk+s][u] * x_g[d][b*HW+pix][cg]
//   d=(16kk+s)/49, kk'=(16kk+s)%49, ki=kk'/7, kj=kk'%7,
//   pix=(u/56+ki-3)*56 + (u%56+kj-3), term dropped if OOB.
// grid (16, 13, 2), block 256: x=s (uniform, fastest -> XCD spread shares u-tile),
// y=u-tile, z=b. Each lane reads one full 64B x_g line per tap (zero line waste),
// each kout element read exactly once. Fixes R6's 73MB over-fetch.
__global__ __launch_bounds__(256) void k4_invol(const float* __restrict__ kout,
                                                float* __restrict__ out) {
  int u = blockIdx.y * 256 + threadIdx.x;     // [0, 3136)
  if (u >= HW) return;
  int s = blockIdx.x;                          // wave-uniform
  int b = blockIdx.z;

  int yrow = u / 56;
  int col  = u - yrow * 56;

  const float* kb = kout + (size_t)b * (KKG * HW) + (size_t)s * HW + u;
  const size_t bHW16 = (size_t)(b * HW) << 4;

  float acc[16];
#pragma unroll
  for (int i = 0; i < 16; ++i) acc[i] = 0.0f;

#pragma unroll 7
  for (int kk = 0; kk < 49; ++kk) {
    int t16 = 16 * kk + s;          // scalar
    int d   = t16 / 49;             // scalar (SALU magic-mul)
    int kkp = t16 - d * 49;         // scalar
    int ki  = kkp / 7;              // scalar
    int kj  = kkp - ki * 7;         // scalar
    int yy = yrow + ki - 3, xx = col + kj - 3;
    float kv = kb[(size_t)kk * (16 * HW)];
    int off;
    if ((unsigned)yy < 56u && (unsigned)xx < 56u) {
      off = yy * 56 + xx;
    } else {
      off = 0;                      // safe address; kv=0 kills the term
      kv = 0.0f;
    }
    const float* xp = g_xg + (((size_t)d * NPIX + off) << 4) + bHW16;
    float4 x0 = *(const float4*)xp;
    float4 x1 = *(const float4*)(xp + 4);
    float4 x2 = *(const float4*)(xp + 8);
    float4 x3 = *(const float4*)(xp + 12);
    acc[0]  += kv * x0.x;  acc[1]  += kv * x0.y;
    acc[2]  += kv * x0.z;  acc[3]  += kv * x0.w;
    acc[4]  += kv * x1.x;  acc[5]  += kv * x1.y;
    acc[6]  += kv * x1.z;  acc[7]  += kv * x1.w;
    acc[8]  += kv * x2.x;  acc[9]  += kv * x2.y;
    acc[10] += kv * x2.z;  acc[11] += kv * x2.w;
    acc[12] += kv * x3.x;  acc[13] += kv * x3.y;
    acc[14] += kv * x3.z;  acc[15] += kv * x3.w;
  }

  // out channel c = 16*cg + s
  float* ob = out + (size_t)b * (C_IN * HW) + (size_t)s * HW + u;
#pragma unroll
  for (int cg = 0; cg < 16; ++cg) ob[(size_t)cg * (16 * HW)] = acc[cg];
}

extern "C" void kernel_launch(void* const* d_in, const int* in_sizes, int n_in,
                              void* d_out, int out_size, void* d_ws, size_t ws_size,
                              hipStream_t stream) {
  const float* x     = (const float*)d_in[0];
  const float* w1    = (const float*)d_in[1];
  const float* b1    = (const float*)d_in[2];
  const float* gamma = (const float*)d_in[3];
  const float* beta  = (const float*)d_in[4];
  const float* w2    = (const float*)d_in[5];
  const float* b2    = (const float*)d_in[6];

  float* out  = (float*)d_out;                       // (B,256,56,56)
  float* kout = out + (size_t)NB * C_IN * HW;        // (B,784,56,56) raw == (B,49,56,56,16)

  k1a_conv1<<<dim3(25, 17, 4), 256, 0, stream>>>(x, w1, w2);
  kRT<<<dim3(25, 80), 256, 0, stream>>>(x, b1);
  kB_conv2<<<dim3(13, 49, NB), 256, 0, stream>>>(gamma, beta, b2, kout);
  k4_invol<<<dim3(16, 13, NB), 256, 0, stream>>>(kout, out);
}

// Round 8
// 125.646 us; speedup vs baseline: 1.1863x; 1.0063x over previous
//
#include <hip/hip_runtime.h>

// Problem constants (B,C,H,W)=(2,256,56,56), Cr=64, K=7, G=16, stride=1
#define HW     3136          // 56*56
#define C_IN   256
#define CR     64
#define KKG    784           // 49*16
#define NB     2             // batch
#define NPIX   6272          // NB*HW
#define NT25   25            // p-tiles of 256 over NPIX
#define BN_EPS 1e-5f

// Device-global scratch (fully rewritten every call; no cross-call state)
__device__ float g_P[4 * CR * NPIX];       // K-split conv1 partials [kc][o][p]
__device__ float g_T[CR * NPIX];           // conv1 output (pre-BN) [o][p]
__device__ float g_bs[2 * CR * NT25];      // per-block partial sum/sumsq [2][o][px]
__device__ float g_xg[16 * NPIX * 16];     // x transposed: [d][p][cg] = x[b][16cg+d][hw]
__device__ float g_w1t[C_IN * CR];         // w1T[c][o] = w1[o][c]   (256 x 64)
__device__ float g_w2t[CR * KKG];          // w2T[c][o] = w2[o][c]   (64 x 784)

// ---------------- K1a: conv1 partials (o-tile 8, split-K by 4) | w-transpose plane ----
// grid (25, 9, 4), block 256.
//   y < 8: conv1 partials, o0=y*8, kc=z. 800 blocks; x re-read 8x (was 16x at o-tile 4).
//   y == 8, z == 0: transpose w1 + w2 (25 blocks, grid-stride); z>0: idle.
__global__ __launch_bounds__(256) void k1a_conv1(const float* __restrict__ x,
                                                 const float* __restrict__ w1,
                                                 const float* __restrict__ w2) {
  if (blockIdx.y == 8) {
    if (blockIdx.z != 0) return;
    int idx = blockIdx.x * 256 + threadIdx.x;
    for (int i = idx; i < C_IN * CR + CR * KKG; i += 25 * 256) {
      if (i < C_IN * CR) {
        int c = i >> 6, o = i & 63;            // w1T[c*64+o] = w1[o*256+c]
        g_w1t[i] = w1[o * C_IN + c];
      } else {
        int j = i - C_IN * CR;
        int c = j / KKG, o = j - c * KKG;      // w2T[c*784+o] = w2[o*64+c]
        g_w2t[j] = w2[o * CR + c];
      }
    }
    return;
  }
  int p = blockIdx.x * 256 + threadIdx.x;   // [0, 6272)
  if (p >= NPIX) return;
  int o0 = blockIdx.y * 8;
  int kc = blockIdx.z;                      // input-channel chunk, 64 chans each
  int b  = p / HW;
  int u  = p - b * HW;

  const float* xb = x + ((size_t)(b * C_IN + kc * 64)) * HW + u;
  const float* w  = w1 + kc * 64;           // w1[o*256 + kc*64 + c] (scalar loads)

  float acc[8];
#pragma unroll
  for (int i = 0; i < 8; ++i) acc[i] = 0.0f;
#pragma unroll 8
  for (int c = 0; c < 64; ++c) {
    float xv = xb[(size_t)c * HW];          // coalesced across lanes
#pragma unroll
    for (int i = 0; i < 8; ++i)
      acc[i] += w[(o0 + i) * C_IN + c] * xv;  // wave-uniform -> s_load
  }
  float* pp = g_P + ((size_t)kc * CR + o0) * NPIX + p;
#pragma unroll
  for (int i = 0; i < 8; ++i) pp[(size_t)i * NPIX] = acc[i];
}

// ---------------- kRT: fused (reduce partials -> T + partial stats) | (transpose x) ----
// grid (25, 80), block 256.
//   y in [0,64): reduce for o=y at p-tile x; write g_T and g_bs[o][px].
//   y in [64,80): transpose slice d=y-64 at p-tile x into g_xg.
__global__ __launch_bounds__(256) void kRT(const float* __restrict__ x,
                                           const float* __restrict__ b1) {
  int p = blockIdx.x * 256 + threadIdx.x;
  if (blockIdx.y < 64) {
    int o = blockIdx.y;
    bool valid = (p < NPIX);
    float v = 0.0f;
    if (valid) {
      v = b1[o]
        + g_P[((size_t)0 * CR + o) * NPIX + p]
        + g_P[((size_t)1 * CR + o) * NPIX + p]
        + g_P[((size_t)2 * CR + o) * NPIX + p]
        + g_P[((size_t)3 * CR + o) * NPIX + p];
      g_T[(size_t)o * NPIX + p] = v;
    }
    float s  = valid ? v : 0.0f;
    float s2 = valid ? v * v : 0.0f;
#pragma unroll
    for (int off = 32; off > 0; off >>= 1) {
      s  += __shfl_down(s, off);
      s2 += __shfl_down(s2, off);
    }
    __shared__ float sd[8];
    int lane = threadIdx.x & 63, wid = threadIdx.x >> 6;
    if (lane == 0) { sd[wid] = s; sd[4 + wid] = s2; }
    __syncthreads();
    if (threadIdx.x == 0) {
      g_bs[o * NT25 + blockIdx.x]             = sd[0] + sd[1] + sd[2] + sd[3];
      g_bs[CR * NT25 + o * NT25 + blockIdx.x] = sd[4] + sd[5] + sd[6] + sd[7];
    }
  } else {
    int d = blockIdx.y - 64;
    if (p >= NPIX) return;
    int b  = (p >= HW) ? 1 : 0;
    int hw = p - b * HW;
    const float* xp = x + ((size_t)(b * C_IN + d)) * HW + hw;
    float r[16];
#pragma unroll
    for (int cg = 0; cg < 16; ++cg)
      r[cg] = xp[(size_t)cg * (16 * HW)];
    float4* dst = (float4*)(g_xg + (((size_t)d * NPIX + p) << 4));
    dst[0] = make_float4(r[0], r[1], r[2], r[3]);
    dst[1] = make_float4(r[4], r[5], r[6], r[7]);
    dst[2] = make_float4(r[8], r[9], r[10], r[11]);
    dst[3] = make_float4(r[12], r[13], r[14], r[15]);
  }
}

// ---------------- kB: kout = w2 @ relu(BN(T)) + b2, BN finalized per-block ----------------
// grid (13, 49, 2), block 256. Each block: 16 output channels x 256 pixels.
// Weights via g_w2t: 64B contiguous per c-iter -> wide s_load.
__global__ __launch_bounds__(256) void kB_conv2(const float* __restrict__ gamma,
                                                const float* __restrict__ beta,
                                                const float* __restrict__ b2,
                                                float* __restrict__ kout) {
  __shared__ float ssc[CR], ssh[CR];
  if (threadIdx.x < CR) {
    int o = threadIdx.x;
    float S = 0.f, S2 = 0.f;
#pragma unroll
    for (int px = 0; px < NT25; ++px) {
      S  += g_bs[o * NT25 + px];
      S2 += g_bs[CR * NT25 + o * NT25 + px];
    }
    const float invN = 1.0f / (float)NPIX;
    float mean = S * invN;
    float var  = S2 * invN - mean * mean;   // population var matches jnp.var
    float inv  = rsqrtf(var + BN_EPS);
    float sc   = gamma[o] * inv;
    ssc[o] = sc;
    ssh[o] = beta[o] - mean * sc;
  }
  __syncthreads();

  int l  = blockIdx.x * 256 + threadIdx.x;
  if (l >= HW) return;
  int o0 = blockIdx.y * 16;
  int b  = blockIdx.z;

  float acc[16];
#pragma unroll
  for (int i = 0; i < 16; ++i) acc[i] = b2[o0 + i];

  const float* Tb = g_T + (size_t)b * HW + l;     // g_T[c*NPIX + b*HW + l]
  const float* wt = g_w2t + o0;                   // w2T[c*784 + o], 64B-aligned rows
#pragma unroll 4
  for (int c = 0; c < CR; ++c) {
    float tv = Tb[(size_t)c * NPIX];
    tv = fmaxf(tv * ssc[c] + ssh[c], 0.0f);       // fused BN + ReLU (LDS broadcast)
#pragma unroll
    for (int i = 0; i < 16; ++i)
      acc[i] += wt[c * KKG + i] * tv;             // contiguous uniform -> wide s_load
  }
  float* kb = kout + (size_t)(b * KKG + o0) * HW + l;
#pragma unroll
  for (int i = 0; i < 16; ++i) kb[(size_t)i * HW] = acc[i];
}

// ---------------- K4: involution, s-per-block, FULL-LINE x_g loads (16 cg/thread) ----
// out[b][16cg+s][u] = sum_kk kout[b][16kk+s][u] * x_g[d][b*HW+pix][cg]
//   d=(16kk+s)/49, kk'=(16kk+s)%49, ki=kk'/7, kj=kk'%7,
//   pix=(u/56+ki-3)*56 + (u%56+kj-3), term dropped if OOB.
// grid (16, 13, 2), block 256: x=s (uniform, fastest -> XCD spread shares u-tile),
// y=u-tile, z=b. Each lane reads one full 64B x_g line per tap (zero line waste),
// each kout element read exactly once.
__global__ __launch_bounds__(256) void k4_invol(const float* __restrict__ kout,
                                                float* __restrict__ out) {
  int u = blockIdx.y * 256 + threadIdx.x;     // [0, 3136)
  if (u >= HW) return;
  int s = blockIdx.x;                          // wave-uniform
  int b = blockIdx.z;

  int yrow = u / 56;
  int col  = u - yrow * 56;

  const float* kb = kout + (size_t)b * (KKG * HW) + (size_t)s * HW + u;
  const size_t bHW16 = (size_t)(b * HW) << 4;

  float acc[16];
#pragma unroll
  for (int i = 0; i < 16; ++i) acc[i] = 0.0f;

#pragma unroll 7
  for (int kk = 0; kk < 49; ++kk) {
    int t16 = 16 * kk + s;          // scalar
    int d   = t16 / 49;             // scalar (SALU magic-mul)
    int kkp = t16 - d * 49;         // scalar
    int ki  = kkp / 7;              // scalar
    int kj  = kkp - ki * 7;         // scalar
    int yy = yrow + ki - 3, xx = col + kj - 3;
    float kv = kb[(size_t)kk * (16 * HW)];
    int off;
    if ((unsigned)yy < 56u && (unsigned)xx < 56u) {
      off = yy * 56 + xx;
    } else {
      off = 0;                      // safe address; kv=0 kills the term
      kv = 0.0f;
    }
    const float* xp = g_xg + (((size_t)d * NPIX + off) << 4) + bHW16;
    float4 x0 = *(const float4*)xp;
    float4 x1 = *(const float4*)(xp + 4);
    float4 x2 = *(const float4*)(xp + 8);
    float4 x3 = *(const float4*)(xp + 12);
    acc[0]  += kv * x0.x;  acc[1]  += kv * x0.y;
    acc[2]  += kv * x0.z;  acc[3]  += kv * x0.w;
    acc[4]  += kv * x1.x;  acc[5]  += kv * x1.y;
    acc[6]  += kv * x1.z;  acc[7]  += kv * x1.w;
    acc[8]  += kv * x2.x;  acc[9]  += kv * x2.y;
    acc[10] += kv * x2.z;  acc[11] += kv * x2.w;
    acc[12] += kv * x3.x;  acc[13] += kv * x3.y;
    acc[14] += kv * x3.z;  acc[15] += kv * x3.w;
  }

  // out channel c = 16*cg + s
  float* ob = out + (size_t)b * (C_IN * HW) + (size_t)s * HW + u;
#pragma unroll
  for (int cg = 0; cg < 16; ++cg) ob[(size_t)cg * (16 * HW)] = acc[cg];
}

extern "C" void kernel_launch(void* const* d_in, const int* in_sizes, int n_in,
                              void* d_out, int out_size, void* d_ws, size_t ws_size,
                              hipStream_t stream) {
  const float* x     = (const float*)d_in[0];
  const float* w1    = (const float*)d_in[1];
  const float* b1    = (const float*)d_in[2];
  const float* gamma = (const float*)d_in[3];
  const float* beta  = (const float*)d_in[4];
  const float* w2    = (const float*)d_in[5];
  const float* b2    = (const float*)d_in[6];

  float* out  = (float*)d_out;                       // (B,256,56,56)
  float* kout = out + (size_t)NB * C_IN * HW;        // (B,784,56,56) raw == (B,49,56,56,16)

  k1a_conv1<<<dim3(25, 9, 4), 256, 0, stream>>>(x, w1, w2);
  kRT<<<dim3(25, 80), 256, 0, stream>>>(x, b1);
  kB_conv2<<<dim3(13, 49, NB), 256, 0, stream>>>(gamma, beta, b2, kout);
  k4_invol<<<dim3(16, 13, NB), 256, 0, stream>>>(kout, out);
}

// Round 9
// 123.694 us; speedup vs baseline: 1.2050x; 1.0158x over previous
//
#include <hip/hip_runtime.h>

// Problem constants (B,C,H,W)=(2,256,56,56), Cr=64, K=7, G=16, stride=1
#define HW     3136          // 56*56
#define C_IN   256
#define CR     64
#define KKG    784           // 49*16
#define NB     2             // batch
#define NPIX   6272          // NB*HW
#define NT25   25            // p-tiles of 256 over NPIX
#define BN_EPS 1e-5f

// Device-global scratch (fully rewritten every call; no cross-call state)
__device__ float g_P[4 * CR * NPIX];       // K-split conv1 partials [kc][o][p]
__device__ float g_T[CR * NPIX];           // conv1 output (pre-BN) [o][p]
__device__ float g_bs[2 * CR * NT25];      // per-block partial sum/sumsq [2][o][px]
__device__ float g_xg[16 * NPIX * 16];     // x transposed: [d][p][cg] = x[b][16cg+d][hw]
__device__ float g_w2t[CR * KKG];          // w2T[c][o] = w2[o][c]   (64 x 784)

// ---------------- K1a: conv1 partials (o-tile 8, split-K 4), XCD-swizzled ----------------
// grid (825) 1-D, block 256.
//   bid < 800: conv partials. XCD-aware decode: kc = (bid%8)>>1 so each kc x-slice
//     (6.4 MB) is touched only by blocks on a fixed PAIR of XCDs (8 MiB combined L2)
//     -> slice stays L2-resident across its 200 re-reading blocks (was: all 8 XCDs
//     thrash on the full 25.7 MB set).
//   bid >= 800: 25 blocks transpose w2 -> g_w2t (read by kB next dispatch).
__global__ __launch_bounds__(256) void k1a_conv1(const float* __restrict__ x,
                                                 const float* __restrict__ w1,
                                                 const float* __restrict__ w2) {
  int bid = blockIdx.x;
  if (bid >= 800) {
    int t = bid - 800;
    int idx = t * 256 + threadIdx.x;
    for (int j = idx; j < CR * KKG; j += 25 * 256) {
      int c = j / KKG, o = j - c * KKG;      // w2T[c*784+o] = w2[o*64+c]
      g_w2t[j] = w2[o * CR + c];
    }
    return;
  }
  int kc     = (bid & 7) >> 1;              // constant per XCD-pair
  int parity = bid & 1;
  int unit   = (bid >> 3) * 2 + parity;     // [0, 200)
  int o0     = (unit & 7) * 8;
  int pt     = unit >> 3;                   // [0, 25)
  int p      = pt * 256 + threadIdx.x;
  if (p >= NPIX) return;
  int b = p / HW;
  int u = p - b * HW;

  const float* xb = x + ((size_t)(b * C_IN + kc * 64)) * HW + u;
  const float* w  = w1 + kc * 64;           // w1[o*256 + kc*64 + c]

  float acc[8];
#pragma unroll
  for (int i = 0; i < 8; ++i) acc[i] = 0.0f;
#pragma unroll 8
  for (int c = 0; c < 64; ++c) {
    float xv = xb[(size_t)c * HW];          // coalesced across lanes, L2-resident slice
#pragma unroll
    for (int i = 0; i < 8; ++i)
      acc[i] += w[(o0 + i) * C_IN + c] * xv;  // wave-uniform -> s_load
  }
  float* pp = g_P + ((size_t)kc * CR + o0) * NPIX + p;
#pragma unroll
  for (int i = 0; i < 8; ++i) pp[(size_t)i * NPIX] = acc[i];
}

// ---------------- kRT: fused (reduce partials -> T + partial stats) | (transpose x) ----
// grid (25, 80), block 256.
//   y in [0,64): reduce for o=y at p-tile x; write g_T and g_bs[o][px].
//   y in [64,80): transpose slice d=y-64 at p-tile x into g_xg.
__global__ __launch_bounds__(256) void kRT(const float* __restrict__ x,
                                           const float* __restrict__ b1) {
  int p = blockIdx.x * 256 + threadIdx.x;
  if (blockIdx.y < 64) {
    int o = blockIdx.y;
    bool valid = (p < NPIX);
    float v = 0.0f;
    if (valid) {
      v = b1[o]
        + g_P[((size_t)0 * CR + o) * NPIX + p]
        + g_P[((size_t)1 * CR + o) * NPIX + p]
        + g_P[((size_t)2 * CR + o) * NPIX + p]
        + g_P[((size_t)3 * CR + o) * NPIX + p];
      g_T[(size_t)o * NPIX + p] = v;
    }
    float s  = valid ? v : 0.0f;
    float s2 = valid ? v * v : 0.0f;
#pragma unroll
    for (int off = 32; off > 0; off >>= 1) {
      s  += __shfl_down(s, off);
      s2 += __shfl_down(s2, off);
    }
    __shared__ float sd[8];
    int lane = threadIdx.x & 63, wid = threadIdx.x >> 6;
    if (lane == 0) { sd[wid] = s; sd[4 + wid] = s2; }
    __syncthreads();
    if (threadIdx.x == 0) {
      g_bs[o * NT25 + blockIdx.x]             = sd[0] + sd[1] + sd[2] + sd[3];
      g_bs[CR * NT25 + o * NT25 + blockIdx.x] = sd[4] + sd[5] + sd[6] + sd[7];
    }
  } else {
    int d = blockIdx.y - 64;
    if (p >= NPIX) return;
    int b  = (p >= HW) ? 1 : 0;
    int hw = p - b * HW;
    const float* xp = x + ((size_t)(b * C_IN + d)) * HW + hw;
    float r[16];
#pragma unroll
    for (int cg = 0; cg < 16; ++cg)
      r[cg] = xp[(size_t)cg * (16 * HW)];
    float4* dst = (float4*)(g_xg + (((size_t)d * NPIX + p) << 4));
    dst[0] = make_float4(r[0], r[1], r[2], r[3]);
    dst[1] = make_float4(r[4], r[5], r[6], r[7]);
    dst[2] = make_float4(r[8], r[9], r[10], r[11]);
    dst[3] = make_float4(r[12], r[13], r[14], r[15]);
  }
}

// ---------------- kB: kout = w2 @ relu(BN(T)) + b2, BN finalized per-block ----------------
// grid (13, 49, 2), block 256. Each block: 16 output channels x 256 pixels.
// Weights via g_w2t: 64B contiguous per c-iter -> wide s_load.
__global__ __launch_bounds__(256) void kB_conv2(const float* __restrict__ gamma,
                                                const float* __restrict__ beta,
                                                const float* __restrict__ b2,
                                                float* __restrict__ kout) {
  __shared__ float ssc[CR], ssh[CR];
  if (threadIdx.x < CR) {
    int o = threadIdx.x;
    float S = 0.f, S2 = 0.f;
#pragma unroll
    for (int px = 0; px < NT25; ++px) {
      S  += g_bs[o * NT25 + px];
      S2 += g_bs[CR * NT25 + o * NT25 + px];
    }
    const float invN = 1.0f / (float)NPIX;
    float mean = S * invN;
    float var  = S2 * invN - mean * mean;   // population var matches jnp.var
    float inv  = rsqrtf(var + BN_EPS);
    float sc   = gamma[o] * inv;
    ssc[o] = sc;
    ssh[o] = beta[o] - mean * sc;
  }
  __syncthreads();

  int l  = blockIdx.x * 256 + threadIdx.x;
  if (l >= HW) return;
  int o0 = blockIdx.y * 16;
  int b  = blockIdx.z;

  float acc[16];
#pragma unroll
  for (int i = 0; i < 16; ++i) acc[i] = b2[o0 + i];

  const float* Tb = g_T + (size_t)b * HW + l;     // g_T[c*NPIX + b*HW + l]
  const float* wt = g_w2t + o0;                   // w2T[c*784 + o], 64B-aligned rows
#pragma unroll 4
  for (int c = 0; c < CR; ++c) {
    float tv = Tb[(size_t)c * NPIX];
    tv = fmaxf(tv * ssc[c] + ssh[c], 0.0f);       // fused BN + ReLU (LDS broadcast)
#pragma unroll
    for (int i = 0; i < 16; ++i)
      acc[i] += wt[c * KKG + i] * tv;             // contiguous uniform -> wide s_load
  }
  float* kb = kout + (size_t)(b * KKG + o0) * HW + l;
#pragma unroll
  for (int i = 0; i < 16; ++i) kb[(size_t)i * HW] = acc[i];
}

// ---------------- K4: involution, s-per-block, FULL-LINE x_g loads (16 cg/thread) ----
// out[b][16cg+s][u] = sum_kk kout[b][16kk+s][u] * x_g[d][b*HW+pix][cg]
//   d=(16kk+s)/49, kk'=(16kk+s)%49, ki=kk'/7, kj=kk'%7,
//   pix=(u/56+ki-3)*56 + (u%56+kj-3), term dropped if OOB.
// grid (16, 13, 2), block 256: x=s (uniform, fastest -> XCD spread shares u-tile),
// y=u-tile, z=b. Each lane reads one full 64B x_g line per tap (zero line waste),
// each kout element read exactly once.
__global__ __launch_bounds__(256) void k4_invol(const float* __restrict__ kout,
                                                float* __restrict__ out) {
  int u = blockIdx.y * 256 + threadIdx.x;     // [0, 3136)
  if (u >= HW) return;
  int s = blockIdx.x;                          // wave-uniform
  int b = blockIdx.z;

  int yrow = u / 56;
  int col  = u - yrow * 56;

  const float* kb = kout + (size_t)b * (KKG * HW) + (size_t)s * HW + u;
  const size_t bHW16 = (size_t)(b * HW) << 4;

  float acc[16];
#pragma unroll
  for (int i = 0; i < 16; ++i) acc[i] = 0.0f;

#pragma unroll 7
  for (int kk = 0; kk < 49; ++kk) {
    int t16 = 16 * kk + s;          // scalar
    int d   = t16 / 49;             // scalar (SALU magic-mul)
    int kkp = t16 - d * 49;         // scalar
    int ki  = kkp / 7;              // scalar
    int kj  = kkp - ki * 7;         // scalar
    int yy = yrow + ki - 3, xx = col + kj - 3;
    float kv = kb[(size_t)kk * (16 * HW)];
    int off;
    if ((unsigned)yy < 56u && (unsigned)xx < 56u) {
      off = yy * 56 + xx;
    } else {
      off = 0;                      // safe address; kv=0 kills the term
      kv = 0.0f;
    }
    const float* xp = g_xg + (((size_t)d * NPIX + off) << 4) + bHW16;
    float4 x0 = *(const float4*)xp;
    float4 x1 = *(const float4*)(xp + 4);
    float4 x2 = *(const float4*)(xp + 8);
    float4 x3 = *(const float4*)(xp + 12);
    acc[0]  += kv * x0.x;  acc[1]  += kv * x0.y;
    acc[2]  += kv * x0.z;  acc[3]  += kv * x0.w;
    acc[4]  += kv * x1.x;  acc[5]  += kv * x1.y;
    acc[6]  += kv * x1.z;  acc[7]  += kv * x1.w;
    acc[8]  += kv * x2.x;  acc[9]  += kv * x2.y;
    acc[10] += kv * x2.z;  acc[11] += kv * x2.w;
    acc[12] += kv * x3.x;  acc[13] += kv * x3.y;
    acc[14] += kv * x3.z;  acc[15] += kv * x3.w;
  }

  // out channel c = 16*cg + s
  float* ob = out + (size_t)b * (C_IN * HW) + (size_t)s * HW + u;
#pragma unroll
  for (int cg = 0; cg < 16; ++cg) ob[(size_t)cg * (16 * HW)] = acc[cg];
}

extern "C" void kernel_launch(void* const* d_in, const int* in_sizes, int n_in,
                              void* d_out, int out_size, void* d_ws, size_t ws_size,
                              hipStream_t stream) {
  const float* x     = (const float*)d_in[0];
  const float* w1    = (const float*)d_in[1];
  const float* b1    = (const float*)d_in[2];
  const float* gamma = (const float*)d_in[3];
  const float* beta  = (const float*)d_in[4];
  const float* w2    = (const float*)d_in[5];
  const float* b2    = (const float*)d_in[6];

  float* out  = (float*)d_out;                       // (B,256,56,56)
  float* kout = out + (size_t)NB * C_IN * HW;        // (B,784,56,56) raw == (B,49,56,56,16)

  k1a_conv1<<<dim3(825), 256, 0, stream>>>(x, w1, w2);
  kRT<<<dim3(25, 80), 256, 0, stream>>>(x, b1);
  kB_conv2<<<dim3(13, 49, NB), 256, 0, stream>>>(gamma, beta, b2, kout);
  k4_invol<<<dim3(16, 13, NB), 256, 0, stream>>>(kout, out);
}